// Round 6
// baseline (217.733 us; speedup 1.0000x reference)
//
#include <hip/hip_runtime.h>
#include <hip/hip_bf16.h>
#include <math.h>

#define Bsz 2
#define Tt  2048
#define Cc  1024
#define Hh  16
#define Dd  64

typedef __attribute__((ext_vector_type(8))) short short8v;
typedef __attribute__((ext_vector_type(4))) short short4v;
typedef __attribute__((ext_vector_type(4))) float f32x4;
typedef __attribute__((ext_vector_type(16))) float f32x16;
typedef __attribute__((ext_vector_type(4))) unsigned int uint4v;

static __device__ __forceinline__ short f2bf(float f) {
  __hip_bfloat16 h = __float2bfloat16(f);
  return __builtin_bit_cast(short, h);
}
static __device__ __forceinline__ float bf2f(short s) {
  unsigned u = ((unsigned)(unsigned short)s) << 16;
  return __builtin_bit_cast(float, u);
}
static __device__ __forceinline__ void gll16(const void* g, void* l) {
  __builtin_amdgcn_global_load_lds((const __attribute__((address_space(1))) unsigned int*)g,
                                   (__attribute__((address_space(3))) unsigned int*)l, 16, 0, 0);
}

// ---------------- prepass: split x into bf16 hi/lo ----------------
__global__ void split_x(const float* __restrict__ x, short* __restrict__ xhi,
                        short* __restrict__ xlo) {
  int t = blockIdx.x * 256 + threadIdx.x;
  const float* s = x + (size_t)t * 8;
  float4 a = *(const float4*)s, b = *(const float4*)(s + 4);
  float vv[8] = {a.x, a.y, a.z, a.w, b.x, b.y, b.z, b.w};
  short8v h, l;
#pragma unroll
  for (int e = 0; e < 8; ++e) {
    short hb = f2bf(vv[e]);
    h[e] = hb;
    l[e] = f2bf(vv[e] - bf2f(hb));
  }
  *(short8v*)(xhi + (size_t)t * 8) = h;
  *(short8v*)(xlo + (size_t)t * 8) = l;
}

// ---------------- prepass: split + transpose W -> Wt[n][k] hi/lo ----------------
__global__ __launch_bounds__(256) void split_wT(const float* __restrict__ Wq,
                                                const float* __restrict__ Wk,
                                                const float* __restrict__ Wv,
                                                const float* __restrict__ Wo,
                                                short* __restrict__ WT) {
  __shared__ float T[64][68];
  const int z = blockIdx.z;
  const float* W = z == 0 ? Wq : z == 1 ? Wk : z == 2 ? Wv : Wo;
  short* oh = WT + (size_t)z * 2097152;
  short* ol = oh + 1048576;
  const int n0 = blockIdx.x * 64, k0 = blockIdx.y * 64;
  const int tid = threadIdx.x;
#pragma unroll
  for (int i = 0; i < 4; ++i) {
    int slot = tid + i * 256;
    int r = slot >> 4, c4 = (slot & 15) << 2;
    *(float4*)&T[r][c4] = *(const float4*)(W + (size_t)(k0 + r) * Cc + n0 + c4);
  }
  __syncthreads();
#pragma unroll
  for (int i = 0; i < 2; ++i) {
    int slot = tid + i * 256;
    int nl = slot >> 3, ks = (slot & 7) << 3;
    short8v h, l;
#pragma unroll
    for (int e = 0; e < 8; ++e) {
      float v = T[ks + e][nl];
      short hb = f2bf(v);
      h[e] = hb;
      l[e] = f2bf(v - bf2f(hb));
    }
    *(short8v*)(oh + (size_t)(n0 + nl) * Cc + k0 + ks) = h;
    *(short8v*)(ol + (size_t)(n0 + nl) * Cc + k0 + ks) = l;
  }
}

// ================= 128x128 split-bf16 GEMM core =================
__device__ __forceinline__ void core128(const short* __restrict__ Ah, const short* __restrict__ Al,
                                        const short* __restrict__ Bh, const short* __restrict__ Bl,
                                        short* AhiL, short* AloL, short* BhiL, short* BloL,
                                        int row0, int col0, int wv, int lane, f32x4 acc[4][4]) {
  const int l15 = lane & 15, g = lane >> 4;
  const int wr = wv >> 1, wc = wv & 1;

  const int srow0 = wv * 32 + (lane >> 2);
  const int srow1 = srow0 + 16;
  const int sch0 = ((lane & 3) ^ ((lane >> 2) & 3)) << 3;
  const size_t aoff0 = (size_t)(row0 + srow0) * Cc + sch0;
  const size_t aoff1 = (size_t)(row0 + srow1) * Cc + sch0;
  const size_t boff0 = (size_t)(col0 + srow0) * Cc + sch0;
  const size_t boff1 = (size_t)(col0 + srow1) * Cc + sch0;
  short* dA0 = AhiL + wv * 1024;  short* dA1 = dA0 + 512;
  short* dAl0 = AloL + wv * 1024; short* dAl1 = dAl0 + 512;
  short* dB0 = BhiL + wv * 1024;  short* dB1 = dB0 + 512;
  short* dBl0 = BloL + wv * 1024; short* dBl1 = dBl0 + 512;

  int aL[4], bL[4];
#pragma unroll
  for (int m = 0; m < 4; ++m) aL[m] = (wr * 64 + m * 16 + l15) * 32 + ((g ^ (l15 & 3)) << 3);
#pragma unroll
  for (int n = 0; n < 4; ++n) bL[n] = (wc * 64 + n * 16 + l15) * 32 + ((g ^ (l15 & 3)) << 3);

  for (int k0 = 0; k0 < Cc; k0 += 32) {
    __syncthreads();
    gll16(Ah + aoff0 + k0, dA0);
    gll16(Ah + aoff1 + k0, dA1);
    gll16(Al + aoff0 + k0, dAl0);
    gll16(Al + aoff1 + k0, dAl1);
    gll16(Bh + boff0 + k0, dB0);
    gll16(Bh + boff1 + k0, dB1);
    gll16(Bl + boff0 + k0, dBl0);
    gll16(Bl + boff1 + k0, dBl1);
    __syncthreads();
    short8v ah[4], al[4], bh[4], bl[4];
#pragma unroll
    for (int m = 0; m < 4; ++m) {
      ah[m] = *(short8v*)&AhiL[aL[m]];
      al[m] = *(short8v*)&AloL[aL[m]];
    }
#pragma unroll
    for (int n = 0; n < 4; ++n) {
      bh[n] = *(short8v*)&BhiL[bL[n]];
      bl[n] = *(short8v*)&BloL[bL[n]];
    }
#pragma unroll
    for (int m = 0; m < 4; ++m)
#pragma unroll
      for (int n = 0; n < 4; ++n) {
        acc[m][n] = __builtin_amdgcn_mfma_f32_16x16x32_bf16(ah[m], bh[n], acc[m][n], 0, 0, 0);
        acc[m][n] = __builtin_amdgcn_mfma_f32_16x16x32_bf16(ah[m], bl[n], acc[m][n], 0, 0, 0);
        acc[m][n] = __builtin_amdgcn_mfma_f32_16x16x32_bf16(al[m], bh[n], acc[m][n], 0, 0, 0);
      }
  }
}

// ---------------- QKV projection GEMM (+rope for Q/K, bf16 out [B,H,T,D]) ----------------
__global__ __launch_bounds__(256, 3) void gemm_qkv(const short* __restrict__ xhi,
                                                   const short* __restrict__ xlo,
                                                   const short* __restrict__ WT,
                                                   const float* __restrict__ bq,
                                                   const float* __restrict__ bk,
                                                   const float* __restrict__ bv,
                                                   short* __restrict__ qb,
                                                   short* __restrict__ kb,
                                                   short* __restrict__ vb) {
  __shared__ short AhiL[4096], AloL[4096], BhiL[4096], BloL[4096];
  const int mode = blockIdx.y;
  const short* Bh = WT + (size_t)mode * 2097152;
  const short* Bl = Bh + 1048576;
  const float* bias = mode == 0 ? bq : mode == 1 ? bk : bv;
  short* Y = mode == 0 ? qb : mode == 1 ? kb : vb;

  const int bid = blockIdx.x;
  const int nid = ((bid & 7) << 5) | (bid >> 3);
  const int row0 = (nid >> 3) * 128, col0 = (nid & 7) * 128;
  const int lane = threadIdx.x & 63, wv = threadIdx.x >> 6;
  const int l15 = lane & 15, g = lane >> 4;
  const int wr = wv >> 1, wc = wv & 1;

  f32x4 acc[4][4];
#pragma unroll
  for (int m = 0; m < 4; ++m)
#pragma unroll
    for (int n = 0; n < 4; ++n) acc[m][n] = (f32x4){0.f, 0.f, 0.f, 0.f};

  core128(xhi, xlo, Bh, Bl, AhiL, AloL, BhiL, BloL, row0, col0, wv, lane, acc);

  const int cbase = col0 + wc * 64;
  const int h = cbase >> 6;
  if (mode < 2) {
    const float scale = (mode == 0) ? 0.18033688f : 1.0f;   // 1/8 * log2(e) folded for Q
#pragma unroll
    for (int n = 0; n < 2; ++n) {
      const int d = n * 16 + l15;
      const float b0 = bias[cbase + d], b1 = bias[cbase + d + 32];
      const float inv = exp2f(-(float)d * (13.2877123795494f / 32.f));
#pragma unroll
      for (int m = 0; m < 4; ++m)
#pragma unroll
        for (int rr = 0; rr < 4; ++rr) {
          int R = row0 + wr * 64 + m * 16 + g * 4 + rr;
          int bI = R >> 11, t = R & (Tt - 1);
          float sn, cs;
          sincosf((float)t * inv, &sn, &cs);
          float v0 = acc[m][n][rr] + b0, v1 = acc[m][n + 2][rr] + b1;
          size_t base = (((size_t)(bI * Hh + h) * Tt + t) << 6) + d;
          Y[base]      = f2bf((v0 * cs - v1 * sn) * scale);
          Y[base + 32] = f2bf((v1 * cs + v0 * sn) * scale);
        }
    }
  } else {
#pragma unroll
    for (int n = 0; n < 2; ++n) {
      const int d = n * 16 + l15;
      const float b0 = bias[cbase + d], b1 = bias[cbase + d + 32];
#pragma unroll
      for (int m = 0; m < 4; ++m)
#pragma unroll
        for (int rr = 0; rr < 4; ++rr) {
          int R = row0 + wr * 64 + m * 16 + g * 4 + rr;
          int bI = R >> 11, t = R & (Tt - 1);
          size_t base = (((size_t)(bI * Hh + h) * Tt + t) << 6) + d;
          Y[base]      = f2bf(acc[m][n][rr] + b0);
          Y[base + 32] = f2bf(acc[m][n + 2][rr] + b1);
        }
    }
  }
}

// ---------------- final output GEMM (128x128 tile, fp32 out) ----------------
__global__ __launch_bounds__(256, 3) void gemm_out(const short* __restrict__ ahi,
                                                   const short* __restrict__ alo,
                                                   const short* __restrict__ WTo,
                                                   const float* __restrict__ bias,
                                                   float* __restrict__ Y) {
  __shared__ short AhiL[4096], AloL[4096], BhiL[4096], BloL[4096];
  const short* Bh = WTo;
  const short* Bl = WTo + 1048576;

  const int bid = blockIdx.x;
  const int nid = ((bid & 7) << 5) | (bid >> 3);
  const int row0 = (nid >> 3) * 128, col0 = (nid & 7) * 128;
  const int lane = threadIdx.x & 63, wv = threadIdx.x >> 6;
  const int l15 = lane & 15, g = lane >> 4;
  const int wr = wv >> 1, wc = wv & 1;

  f32x4 acc[4][4];
#pragma unroll
  for (int m = 0; m < 4; ++m)
#pragma unroll
    for (int n = 0; n < 4; ++n) acc[m][n] = (f32x4){0.f, 0.f, 0.f, 0.f};

  core128(ahi, alo, Bh, Bl, AhiL, AloL, BhiL, BloL, row0, col0, wv, lane, acc);

  const int cbase = col0 + wc * 64;
#pragma unroll
  for (int n = 0; n < 2; ++n) {
    const int ccol = cbase + n * 16 + l15;
    const float b0 = bias[ccol], b1 = bias[ccol + 32];
#pragma unroll
    for (int m = 0; m < 4; ++m)
#pragma unroll
      for (int rr = 0; rr < 4; ++rr) {
        int R = row0 + wr * 64 + m * 16 + g * 4 + rr;
        Y[(size_t)R * Cc + ccol]      = acc[m][n][rr] + b0;
        Y[(size_t)R * Cc + ccol + 32] = acc[m][n + 2][rr] + b1;
      }
  }
}

// ================= MFMA flash attention v3: 32x32 MFMA =================
// 4 waves x 32 queries = 128-q blocks; 512 blocks (2/CU), load-balanced {Q,15-Q}
// per CU. Swapped QK^T: S^T = mfma32(K, Q) accumulated over 4 dim-tiles ->
// lane owns query col = lane&31, keys (r&3)+8(r>>2)+4*(lane>>5).
// PV: O^T = mfma32(V^T, P); P-frags built via bf16 pair-pack + shfl_xor(32).
// K staged via global_load_lds + XOR-chunk swizzle; V^T staged conflict-free
// (thread = (key-pair, dim-block)). Double-buffered, 1 barrier/chunk.
__global__ __launch_bounds__(256, 2) void attn_mfma(const short* __restrict__ q,
                                                    const short* __restrict__ k,
                                                    const short* __restrict__ v,
                                                    short* __restrict__ ohi,
                                                    short* __restrict__ olo) {
  const int n = blockIdx.x;           // 512
  const int xcd = n & 7;
  const int slot = n >> 3;            // 0..63
  const int cu = slot & 31, jj = slot >> 5;
  const int bhj = (jj ? 2 : 0) + (cu >> 4);
  const int Q = jj ? (15 - (cu & 15)) : (cu & 15);
  const int bh = xcd * 4 + bhj;
  const int q0 = Q * 128;

  const int tid = threadIdx.x;
  const int lane = tid & 63;
  const int wv = tid >> 6;
  const int l31 = lane & 31;
  const int hb = lane >> 5;           // half-wave
  const int qbase = q0 + wv * 32;
  const int tq = qbase + l31;

  const short* qgb = q + (size_t)bh * Tt * Dd;
  const short* kgb = k + (size_t)bh * Tt * Dd;
  const short* vgb = v + (size_t)bh * Tt * Dd;

  // Q fragments: MFMA i covers dims 16i + 8hb .. +7
  const short* qp = qgb + (size_t)tq * Dd + 8 * hb;
  short8v qf[4];
#pragma unroll
  for (int i = 0; i < 4; ++i) qf[i] = *(const short8v*)(qp + 16 * i);

  __shared__ short Klds[2][32 * 64];
  __shared__ short Vt[2][64 * 40];

  // K staging (gll): wave wv stages rows 8wv..8wv+7; phys chunk = lane&7,
  // source log chunk = (lane&7) ^ (row&7)
  const int r8 = lane >> 3;
  const size_t ksrc_off = (size_t)(wv * 8 + r8) * Dd + (((lane & 7) ^ r8) << 3);

  // V^T staging: thread = (key-pair kp, dim-block db) -> conflict-free writes
  const int kp = tid & 15;            // keys 2kp, 2kp+1
  const int db = tid >> 4;            // dims 4db..4db+3
  const size_t vsrc_off = (size_t)(2 * kp) * Dd + 4 * db;

  // K fragment read offsets: row l31, log chunk 2i+hb, phys = ^ (l31&7)
  int koff[4];
#pragma unroll
  for (int i = 0; i < 4; ++i) koff[i] = l31 * 64 + (((2 * i + hb) ^ (l31 & 7)) << 3);

  f32x16 oacc[2];
#pragma unroll
  for (int t = 0; t < 2; ++t)
#pragma unroll
    for (int r = 0; r < 16; ++r) oacc[t][r] = 0.f;
  float mrun = -1e30f, lrun = 0.f;

  const int cs0 = (q0 - 511) > 0 ? (q0 - 511) : 0;
  const int cstart = cs0 & ~31;
  const int nch = (Tt - cstart) >> 5;

  short4v va, vb2;

  // ---- prologue ----
  gll16(kgb + (size_t)cstart * Dd + ksrc_off, &Klds[0][wv * 512]);
  va  = *(const short4v*)(vgb + (size_t)cstart * Dd + vsrc_off);
  vb2 = *(const short4v*)(vgb + (size_t)cstart * Dd + vsrc_off + Dd);
#pragma unroll
  for (int e = 0; e < 4; ++e) {
    unsigned w = (unsigned)(unsigned short)va[e] | ((unsigned)(unsigned short)vb2[e] << 16);
    *(unsigned*)&Vt[0][(4 * db + e) * 40 + 2 * kp] = w;
  }
  if (nch > 1) {
    va  = *(const short4v*)(vgb + (size_t)(cstart + 32) * Dd + vsrc_off);
    vb2 = *(const short4v*)(vgb + (size_t)(cstart + 32) * Dd + vsrc_off + Dd);
  }
  __syncthreads();

  for (int ci = 0; ci < nch; ++ci) {
    const int jt = cstart + (ci << 5);
    const int cur = ci & 1;

    if (ci + 1 < nch) {
      gll16(kgb + (size_t)(jt + 32) * Dd + ksrc_off, &Klds[cur ^ 1][wv * 512]);
#pragma unroll
      for (int e = 0; e < 4; ++e) {
        unsigned w = (unsigned)(unsigned short)va[e] | ((unsigned)(unsigned short)vb2[e] << 16);
        *(unsigned*)&Vt[cur ^ 1][(4 * db + e) * 40 + 2 * kp] = w;
      }
      if (ci + 2 < nch) {
        va  = *(const short4v*)(vgb + (size_t)(jt + 64) * Dd + vsrc_off);
        vb2 = *(const short4v*)(vgb + (size_t)(jt + 64) * Dd + vsrc_off + Dd);
      }
    }

    if (jt + 32 > qbase - 511) {
      const short* kbuf = &Klds[cur][0];
      f32x16 se;
#pragma unroll
      for (int r = 0; r < 16; ++r) se[r] = 0.f;
#pragma unroll
      for (int i = 0; i < 4; ++i) {
        short8v kf = *(short8v*)&kbuf[koff[i]];
        se = __builtin_amdgcn_mfma_f32_32x32x16_bf16(kf, qf[i], se, 0, 0, 0);
      }

      if (jt < qbase - 480) {   // boundary: window mask
        int th = tq - 511 - jt;
#pragma unroll
        for (int r = 0; r < 16; ++r) {
          int row = (r & 3) + 8 * (r >> 2) + 4 * hb;
          if (row < th) se[r] = -1e30f;
        }
      }

      float cmax = se[0];
#pragma unroll
      for (int r = 1; r < 16; ++r) cmax = fmaxf(cmax, se[r]);
      cmax = fmaxf(cmax, __shfl_xor(cmax, 32));

      if (!__all(cmax <= mrun + 8.0f)) {
        float mnew = fmaxf(fmaxf(mrun, cmax), -1e29f);
        float fac = exp2f(mrun - mnew);
        lrun *= fac;
#pragma unroll
        for (int t = 0; t < 2; ++t)
#pragma unroll
          for (int r = 0; r < 16; ++r) oacc[t][r] *= fac;
        mrun = mnew;
      }

      float p[16], psum = 0.f;
#pragma unroll
      for (int r = 0; r < 16; ++r) { p[r] = exp2f(se[r] - mrun); psum += p[r]; }
      psum += __shfl_xor(psum, 32);
      lrun += psum;

      // pack p into bf16 pairs; build PV B-frags via half-wave exchange
      unsigned pk[8], pw[8];
#pragma unroll
      for (int i = 0; i < 8; ++i) {
        pk[i] = (unsigned)(unsigned short)f2bf(p[2 * i]) |
                ((unsigned)(unsigned short)f2bf(p[2 * i + 1]) << 16);
      }
#pragma unroll
      for (int i = 0; i < 8; ++i) pw[i] = __shfl_xor(pk[i], 32);

      uint4v f0, f1;
      f0[0] = hb ? pw[2] : pk[0];
      f0[1] = hb ? pw[3] : pk[1];
      f0[2] = hb ? pk[2] : pw[0];
      f0[3] = hb ? pk[3] : pw[1];
      f1[0] = hb ? pw[6] : pk[4];
      f1[1] = hb ? pw[7] : pk[5];
      f1[2] = hb ? pk[6] : pw[4];
      f1[3] = hb ? pk[7] : pw[5];
      short8v pf0 = __builtin_bit_cast(short8v, f0);
      short8v pf1 = __builtin_bit_cast(short8v, f1);

#pragma unroll
      for (int t = 0; t < 2; ++t) {
        const int vrow = (32 * t + l31) * 40;
        short8v v0 = *(short8v*)&Vt[cur][vrow + (hb << 3)];
        short8v v1 = *(short8v*)&Vt[cur][vrow + ((2 + hb) << 3)];
        oacc[t] = __builtin_amdgcn_mfma_f32_32x32x16_bf16(v0, pf0, oacc[t], 0, 0, 0);
        oacc[t] = __builtin_amdgcn_mfma_f32_32x32x16_bf16(v1, pf1, oacc[t], 0, 0, 0);
      }
    }
    __syncthreads();
  }

  // ---- epilogue: split hi/lo bf16, write [B,T,C] ----
  const float invl = 1.f / lrun;
  const int bI = bh >> 4, hd = bh & 15;
  short* oh = ohi + ((size_t)(bI * Tt + tq)) * Cc + hd * Dd;
  short* ol = olo + ((size_t)(bI * Tt + tq)) * Cc + hd * Dd;
#pragma unroll
  for (int t = 0; t < 2; ++t)
#pragma unroll
    for (int rq = 0; rq < 4; ++rq) {
      short4v hv, lv;
#pragma unroll
      for (int rr = 0; rr < 4; ++rr) {
        float val = oacc[t][4 * rq + rr] * invl;
        short hbv = f2bf(val);
        hv[rr] = hbv;
        lv[rr] = f2bf(val - bf2f(hbv));
      }
      int d0 = 32 * t + 8 * rq + 4 * hb;
      *(short4v*)(oh + d0) = hv;
      *(short4v*)(ol + d0) = lv;
    }
}

extern "C" void kernel_launch(void* const* d_in, const int* in_sizes, int n_in,
                              void* d_out, int out_size, void* d_ws, size_t ws_size,
                              hipStream_t stream) {
  const float* x  = (const float*)d_in[0];
  const float* Wq = (const float*)d_in[1];
  const float* bq = (const float*)d_in[2];
  const float* Wk = (const float*)d_in[3];
  const float* bk = (const float*)d_in[4];
  const float* Wv = (const float*)d_in[5];
  const float* bv = (const float*)d_in[6];
  const float* Wo = (const float*)d_in[7];
  const float* bo = (const float*)d_in[8];

  short* ws16 = (short*)d_ws;
  short* xhi = ws16;                  // 8MB; reused as attn_hi after projections
  short* xlo = ws16 + 4194304;        // 8MB; reused as attn_lo
  short* WT  = ws16 + 8388608;        // 16MB
  short* qb  = ws16 + 16777216;       // 8MB bf16 [B,H,T,D]
  short* kb  = ws16 + 20971520;
  short* vb  = ws16 + 25165824;

  split_x<<<2048, 256, 0, stream>>>(x, xhi, xlo);
  split_wT<<<dim3(16, 16, 4), 256, 0, stream>>>(Wq, Wk, Wv, Wo, WT);

  gemm_qkv<<<dim3(256, 3), 256, 0, stream>>>(xhi, xlo, WT, bq, bk, bv, qb, kb, vb);

  attn_mfma<<<512, 256, 0, stream>>>(qb, kb, vb, xhi, xlo);

  gemm_out<<<256, 256, 0, stream>>>(xhi, xlo, WT + 6 * 1048576, bo, (float*)d_out);
}